// Round 5
// baseline (761.133 us; speedup 1.0000x reference)
//
#include <hip/hip_runtime.h>
#include <hip/hip_bf16.h>

// GQA flash attention fwd, causal + sliding window 1024.
// B=2, S=2048, Hq=32, Hkv=8 (group 4), D=128.
// FP32 in/out; bf16 MFMA compute, fp32 accum. Finite sentinels only.
// V^T is stored in LDS with an XOR column swizzle so the transpose stores
// are ~2-way (free) instead of 16-way bank-conflicted.

#define H_Q 32
#define H_KV 8
#define HDIM 128
#define SEQLEN 2048
#define NBATCH 2
#define WIN 1024
#define QK_SCALE 0.08838834764831845f
#define LOG2E 1.4426950408889634f
#define SCALE_LOG2E (QK_SCALE * LOG2E)

#define NEG_BIG  (-3.0e38f)
#define NEG_CLMP (-1.0e30f)

#define QPITCH (H_Q * HDIM)   // 4096 floats
#define KPITCH (H_KV * HDIM)  // 1024 floats

typedef __attribute__((ext_vector_type(8))) short  short8;   // 8 bf16 = 4 VGPR
typedef __attribute__((ext_vector_type(4))) short  short4v;  // 4 bf16 = 8 B
typedef __attribute__((ext_vector_type(4))) float  floatx4;

static __device__ __forceinline__ short bf16bits(float x) {
    return __builtin_bit_cast(short, __float2bfloat16(x));
}

__global__ __launch_bounds__(256, 3)
void fa_fwd(const float* __restrict__ Q,
            const float* __restrict__ K,
            const float* __restrict__ V,
            float* __restrict__ O)
{
    __shared__ __align__(16) short lds_k[64][136];   // K tile [key][d]
    __shared__ __align__(16) short lds_vt[128][72];  // V^T, XOR-swizzled columns
    __shared__ __align__(16) short lds_p[4][16][72]; // per-wave P [q][key]

    const int bi  = blockIdx.x;
    const int qt  = 31 - (bi & 31);   // heavy q-tiles (more k-tiles) dispatch first
    const int h   = (bi >> 5) & 31;
    const int b   = bi >> 10;
    const int kvh = h >> 2;
    const int q0  = qt << 6;

    const int tid  = threadIdx.x;
    const int wid  = tid >> 6;
    const int lane = tid & 63;
    const int ln16 = lane & 15;
    const int lg   = lane >> 4;

    const float* Qb = Q + (size_t)b * SEQLEN * QPITCH + (size_t)h * HDIM;
    const float* Kb = K + (size_t)b * SEQLEN * KPITCH + (size_t)kvh * HDIM;
    const float* Vb = V + (size_t)b * SEQLEN * KPITCH + (size_t)kvh * HDIM;
    float*       Ob = O + (size_t)b * SEQLEN * QPITCH + (size_t)h * HDIM;

    // ---- Q fragments (A operand), registers for whole kernel.
    short8 qf[4];
    {
        const int qrow = q0 + wid * 16 + ln16;
        const float* qs = Qb + (size_t)qrow * QPITCH + lg * 8;
        #pragma unroll
        for (int kk = 0; kk < 4; ++kk) {
            floatx4 a = *(const floatx4*)(qs + kk * 32);
            floatx4 c = *(const floatx4*)(qs + kk * 32 + 4);
            short8 f;
            #pragma unroll
            for (int j = 0; j < 4; ++j) { f[j] = bf16bits(a[j]); f[4 + j] = bf16bits(c[j]); }
            qf[kk] = f;
        }
    }

    floatx4 oacc[8];
    #pragma unroll
    for (int i = 0; i < 8; ++i) oacc[i] = (floatx4){0.f, 0.f, 0.f, 0.f};
    float m_r[4], l_r[4];
    #pragma unroll
    for (int r = 0; r < 4; ++r) { m_r[r] = NEG_BIG; l_r[r] = 0.f; }

    int kvlo = q0 - (WIN - 1);
    if (kvlo < 0) kvlo = 0;
    kvlo &= ~63;

    for (int kk0 = kvlo; kk0 <= q0; kk0 += 64) {
        __syncthreads();              // previous tile's LDS reads done
        // ---- stage K [key][d] and swizzled V^T into LDS (fp32->bf16 in regs)
        {
            #pragma unroll
            for (int i = 0; i < 8; ++i) {
                const int fi  = i * 256 + tid;     // 0..2047
                const int key = fi >> 5;           // 0..63
                const int m   = fi & 31;
                const int c4  = m * 4;             // d col 0,4,...,124
                const size_t grow = (size_t)(kk0 + key) * KPITCH + c4;
                floatx4 kv = *(const floatx4*)(Kb + grow);
                short4v ks;
                #pragma unroll
                for (int j = 0; j < 4; ++j) ks[j] = bf16bits(kv[j]);
                *(short4v*)&lds_k[key][c4] = ks;
                floatx4 vv = *(const floatx4*)(Vb + grow);
                // XOR-swizzled transpose store: element (key, d=c4+j) lives at
                // column ((key>>3) ^ ((d>>3)&7))*8 + (key&7). (d>>3 == c4>>3
                // for j<4 since c4 % 4 == 0.)
                const int colb = (((key >> 3) ^ ((c4 >> 3) & 7)) << 3) + (key & 7);
                #pragma unroll
                for (int j = 0; j < 4; ++j)
                    lds_vt[c4 + j][colb] = bf16bits(vv[j]);
            }
        }
        __syncthreads();

        // ---- S = Q K^T  (16 MFMAs per wave)
        float sc[4][4];
        #pragma unroll
        for (int nt = 0; nt < 4; ++nt) {
            floatx4 acc = (floatx4){0.f, 0.f, 0.f, 0.f};
            #pragma unroll
            for (int kk = 0; kk < 4; ++kk) {
                short8 kf = *(const short8*)&lds_k[nt * 16 + ln16][kk * 32 + lg * 8];
                acc = __builtin_amdgcn_mfma_f32_16x16x32_bf16(qf[kk], kf, acc, 0, 0, 0);
            }
            #pragma unroll
            for (int r = 0; r < 4; ++r) sc[nt][r] = acc[r];
        }

        // ---- scale + mask
        const bool full = (kk0 + 63 <= q0) && (kk0 >= q0 - 960);
        float pm[4];
        #pragma unroll
        for (int r = 0; r < 4; ++r) pm[r] = NEG_BIG;
        if (full) {
            #pragma unroll
            for (int nt = 0; nt < 4; ++nt)
                #pragma unroll
                for (int r = 0; r < 4; ++r) {
                    sc[nt][r] *= SCALE_LOG2E;
                    pm[r] = fmaxf(pm[r], sc[nt][r]);
                }
        } else {
            #pragma unroll
            for (int nt = 0; nt < 4; ++nt) {
                const int kcol = kk0 + nt * 16 + ln16;
                #pragma unroll
                for (int r = 0; r < 4; ++r) {
                    const int qrow = q0 + wid * 16 + lg * 4 + r;
                    const bool ok = (kcol <= qrow) && (qrow - kcol < WIN);
                    sc[nt][r] = ok ? sc[nt][r] * SCALE_LOG2E : NEG_BIG;
                    pm[r] = fmaxf(pm[r], sc[nt][r]);
                }
            }
        }
        #pragma unroll
        for (int r = 0; r < 4; ++r)
            #pragma unroll
            for (int off = 1; off < 16; off <<= 1)
                pm[r] = fmaxf(pm[r], __shfl_xor(pm[r], off, 16));

        float alpha[4], mne[4];
        #pragma unroll
        for (int r = 0; r < 4; ++r) {
            const float mn = fmaxf(m_r[r], pm[r]);
            const float me = fmaxf(mn, NEG_CLMP);
            alpha[r] = exp2f(m_r[r] - me);
            m_r[r] = mn;
            mne[r] = me;
        }

        // ---- P = exp2(s - m) -> wave-private LDS [q][key]
        float psum[4] = {0.f, 0.f, 0.f, 0.f};
        #pragma unroll
        for (int nt = 0; nt < 4; ++nt)
            #pragma unroll
            for (int r = 0; r < 4; ++r) {
                const float p = exp2f(sc[nt][r] - mne[r]);
                psum[r] += p;
                lds_p[wid][lg * 4 + r][nt * 16 + ln16] = bf16bits(p);
            }
        #pragma unroll
        for (int r = 0; r < 4; ++r) {
            #pragma unroll
            for (int off = 1; off < 16; off <<= 1)
                psum[r] += __shfl_xor(psum[r], off, 16);
            l_r[r] = l_r[r] * alpha[r] + psum[r];
        }
        #pragma unroll
        for (int dt = 0; dt < 8; ++dt)
            #pragma unroll
            for (int r = 0; r < 4; ++r) oacc[dt][r] *= alpha[r];

        // lds_p is wave-private: compiler+lgkmcnt fence suffices (no s_barrier).
        __threadfence_block();

        // ---- O += P V  (16 MFMAs per wave)
        #pragma unroll
        for (int ks = 0; ks < 2; ++ks) {
            short8 pf = *(const short8*)&lds_p[wid][ln16][ks * 32 + lg * 8];
            #pragma unroll
            for (int dt = 0; dt < 8; ++dt) {
                const int d = dt * 16 + ln16;
                const int col = (((ks * 4 + lg) ^ ((d >> 3) & 7)) << 3);
                short8 vf = *(const short8*)&lds_vt[d][col];
                oacc[dt] = __builtin_amdgcn_mfma_f32_16x16x32_bf16(pf, vf, oacc[dt], 0, 0, 0);
            }
        }
    }

    // ---- epilogue: normalize and store fp32
    #pragma unroll
    for (int r = 0; r < 4; ++r) {
        const float inv = 1.0f / l_r[r];
        const int qrow = q0 + wid * 16 + lg * 4 + r;
        float* dst = Ob + (size_t)qrow * QPITCH;
        #pragma unroll
        for (int dt = 0; dt < 8; ++dt)
            dst[dt * 16 + ln16] = oacc[dt][r] * inv;
    }
}

extern "C" void kernel_launch(void* const* d_in, const int* in_sizes, int n_in,
                              void* d_out, int out_size, void* d_ws, size_t ws_size,
                              hipStream_t stream) {
    const float* Q = (const float*)d_in[0];
    const float* K = (const float*)d_in[1];
    const float* V = (const float*)d_in[2];
    float* O = (float*)d_out;
    dim3 grid(NBATCH * H_Q * (SEQLEN / 64));
    fa_fwd<<<grid, 256, 0, stream>>>(Q, K, V, O);
}